// Round 1
// baseline (276.217 us; speedup 1.0000x reference)
//
#include <hip/hip_runtime.h>
#include <math.h>

#define NN 2048
#define NEG_SLOPE 0.2f

// ---------------- GEMM fp32: C[M,N] = A[M,K] @ B[K,N], row-major ----------------
// BM=BN=64, BK=16, 256 threads, 4x4 per thread. M,N mult of 64, K mult of 16.
__global__ __launch_bounds__(256) void gemm_fp32(
    const float* __restrict__ A, const float* __restrict__ B, float* __restrict__ C,
    int N, int K)
{
    __shared__ __align__(16) float As[16][68];   // [k][row] (transposed A tile)
    __shared__ __align__(16) float Bs[16][68];   // [k][col]
    const int t = threadIdx.x;
    const int tx = t & 15, ty = t >> 4;
    const int i0 = blockIdx.y * 64, c0 = blockIdx.x * 64;
    float acc[4][4] = {};
    for (int k0 = 0; k0 < K; k0 += 16) {
        {
            const int row = t >> 2, kq = (t & 3) << 2;
            const float4 av = *(const float4*)&A[(size_t)(i0 + row) * K + k0 + kq];
            As[kq + 0][row] = av.x; As[kq + 1][row] = av.y;
            As[kq + 2][row] = av.z; As[kq + 3][row] = av.w;
            const int kk = t >> 4, n4 = (t & 15) << 2;
            *(float4*)&Bs[kk][n4] = *(const float4*)&B[(size_t)(k0 + kk) * N + c0 + n4];
        }
        __syncthreads();
        #pragma unroll
        for (int kk = 0; kk < 16; ++kk) {
            const float4 av = *(const float4*)&As[kk][ty << 2];
            const float4 bv = *(const float4*)&Bs[kk][tx << 2];
            const float a_[4] = {av.x, av.y, av.z, av.w};
            const float b_[4] = {bv.x, bv.y, bv.z, bv.w};
            #pragma unroll
            for (int r = 0; r < 4; ++r)
                #pragma unroll
                for (int c = 0; c < 4; ++c)
                    acc[r][c] += a_[r] * b_[c];
        }
        __syncthreads();
    }
    #pragma unroll
    for (int r = 0; r < 4; ++r) {
        const float4 o = make_float4(acc[r][0], acc[r][1], acc[r][2], acc[r][3]);
        *(float4*)&C[(size_t)(i0 + (ty << 2) + r) * N + c0 + (tx << 2)] = o;
    }
}

// ---------------- attention scores: sl[i,h] = g[i,h,:].a_l, sr = g[i,h,:].a_r ---
// one wave per (i,h); dh = per-head feature count (mult of 64)
__global__ __launch_bounds__(256) void score_fp32(
    const float* __restrict__ g, const float* __restrict__ a,
    float* __restrict__ sl, float* __restrict__ sr,
    int gcols, int dh, int nh)
{
    const int wid = (int)((blockIdx.x * blockDim.x + threadIdx.x) >> 6);
    const int lane = threadIdx.x & 63;
    const int i = wid / nh, h = wid - i * nh;
    if (i >= NN) return;
    float vsl = 0.f, vsr = 0.f;
    for (int q = 0; q < dh; q += 64) {
        const float gv = g[(size_t)i * gcols + h * dh + q + lane];
        vsl += gv * a[q + lane];
        vsr += gv * a[dh + q + lane];
    }
    #pragma unroll
    for (int off = 32; off > 0; off >>= 1) {
        vsl += __shfl_down(vsl, off);
        vsr += __shfl_down(vsr, off);
    }
    if (lane == 0) { sl[wid] = vsl; sr[wid] = vsr; }
}

// ---------------- fused masked-softmax attention + PV + (ELU) ----------------
// out[i, c0+f] = (1/Z_i) * sum_j adj[i,j] * exp(LR(sl[i]+sr[j])) * g[j, c0+f]
// block: 32 rows x 64 cols; grid.x = N/32 i-tiles, grid.y = gcols/64 col-blocks.
// hsel < 0 -> head = blockIdx.y (layer 1); else fixed head index (layer 2).
__global__ __launch_bounds__(256) void attn_fp32(
    const float* __restrict__ g, const float* __restrict__ slv, const float* __restrict__ srv,
    const int* __restrict__ adj, float* __restrict__ out,
    int gcols, int nh, int hsel, int do_elu)
{
    const int t = threadIdx.x;
    const int i0 = blockIdx.x * 32;
    const int cb = blockIdx.y;
    const int c0 = cb << 6;
    const int hsl = (hsel < 0) ? cb : hsel;

    __shared__ int adj_s[32][65];                 // pad 65: conflict-free transpose read
    __shared__ __align__(16) float w_s[64][36];   // pad 36: b128-aligned, 2-way writes
    __shared__ __align__(16) float gs[64][64];
    __shared__ float sr_s[64];
    __shared__ float sl_s[32];
    __shared__ float z_s[8][32];
    __shared__ float zf[32];

    const int igrp = t >> 5;   // 0..7 : rows 4*igrp..4*igrp+3
    const int fgrp = t & 31;   // cols 2*fgrp, 2*fgrp+1
    const int w_ii = t & 31;   // w-phase: row
    const int w_jb = t >> 5;   // w-phase: jj block

    if (t < 32) sl_s[t] = slv[(size_t)(i0 + t) * nh + hsl];

    float acc[4][2] = {};
    float zacc = 0.f;

    for (int j0 = 0; j0 < NN; j0 += 64) {
        // ---- stage adj (32x64), sr (64), g (64x64), all coalesced ----
        #pragma unroll
        for (int r = 0; r < 8; ++r) {
            const int idx = (r << 8) + t;
            const int ii = idx >> 6, jj = idx & 63;
            adj_s[ii][jj] = adj[(size_t)(i0 + ii) * NN + j0 + jj];
        }
        if (t < 64) sr_s[t] = srv[(size_t)(j0 + t) * nh + hsl];
        #pragma unroll
        for (int q = 0; q < 4; ++q) {
            const int idx = (q << 8) + t;
            const int jj = idx >> 4, f4 = (idx & 15) << 2;
            *(float4*)&gs[jj][f4] = *(const float4*)&g[(size_t)(j0 + jj) * gcols + c0 + f4];
        }
        __syncthreads();
        // ---- w = adj * exp(leakyrelu(sl+sr)); accumulate Z partials ----
        {
            const float sle = sl_s[w_ii];
            #pragma unroll
            for (int r = 0; r < 8; ++r) {
                const int jj = (w_jb << 3) + r;
                float e = sle + sr_s[jj];
                e = (e > 0.f) ? e : NEG_SLOPE * e;
                const float w = adj_s[w_ii][jj] ? __expf(e) : 0.f;
                w_s[jj][w_ii] = w;
                zacc += w;
            }
        }
        __syncthreads();
        // ---- PV: acc[r][c] += w[jj][ii] * g[jj][f] ----
        #pragma unroll 8
        for (int jj = 0; jj < 64; ++jj) {
            const float4 wv = *(const float4*)&w_s[jj][igrp << 2];   // broadcast read
            const float2 gv = *(const float2*)&gs[jj][fgrp << 1];
            acc[0][0] += wv.x * gv.x; acc[0][1] += wv.x * gv.y;
            acc[1][0] += wv.y * gv.x; acc[1][1] += wv.y * gv.y;
            acc[2][0] += wv.z * gv.x; acc[2][1] += wv.z * gv.y;
            acc[3][0] += wv.w * gv.x; acc[3][1] += wv.w * gv.y;
        }
        __syncthreads();
    }
    // ---- reduce Z over the 8 jj-blocks ----
    z_s[w_jb][w_ii] = zacc;
    __syncthreads();
    if (t < 32) {
        float z = 0.f;
        #pragma unroll
        for (int b = 0; b < 8; ++b) z += z_s[b][t];
        zf[t] = z;
    }
    __syncthreads();
    // ---- normalize, optional ELU, store ----
    #pragma unroll
    for (int r = 0; r < 4; ++r) {
        const float rz = 1.0f / zf[(igrp << 2) + r];
        float o0 = acc[r][0] * rz;
        float o1 = acc[r][1] * rz;
        if (do_elu) {
            o0 = (o0 > 0.f) ? o0 : (__expf(o0) - 1.f);
            o1 = (o1 > 0.f) ? o1 : (__expf(o1) - 1.f);
        }
        *(float2*)&out[(size_t)(i0 + (igrp << 2) + r) * gcols + c0 + (fgrp << 1)] =
            make_float2(o0, o1);
    }
}

extern "C" void kernel_launch(void* const* d_in, const int* in_sizes, int n_in,
                              void* d_out, int out_size, void* d_ws, size_t ws_size,
                              hipStream_t stream)
{
    const float* x   = (const float*)d_in[0];   // 2048 x 512
    const int*   adj = (const int*)  d_in[1];   // 2048 x 2048
    const float* W1  = (const float*)d_in[2];   // 512 x 512
    const float* a1  = (const float*)d_in[3];   // 128
    const float* W2  = (const float*)d_in[4];   // 512 x 256
    const float* a2  = (const float*)d_in[5];   // 512
    float* out = (float*)d_out;                 // 2048 x 256

    float* g1  = (float*)d_ws;                  // 2048*512
    float* hb  = g1 + 2048 * 512;               // 2048*512 (elu'd layer-1 out)
    float* g2  = hb + 2048 * 512;               // 2048*256
    float* sl1 = g2 + 2048 * 256;               // 2048*8
    float* sr1 = sl1 + 2048 * 8;                // 2048*8
    float* sl2 = sr1 + 2048 * 8;                // 2048
    float* sr2 = sl2 + 2048;                    // 2048

    // ---- layer 1: g1 = x@W1; scores; fused attn (+ELU) -> hb ----
    gemm_fp32<<<dim3(512 / 64, 2048 / 64), 256, 0, stream>>>(x, W1, g1, 512, 512);
    score_fp32<<<dim3((2048 * 8) / 4), 256, 0, stream>>>(g1, a1, sl1, sr1, 512, 64, 8);
    attn_fp32<<<dim3(2048 / 32, 8), 256, 0, stream>>>(g1, sl1, sr1, adj, hb, 512, 8, -1, 1);

    // ---- layer 2: g2 = hb@W2; scores; fused attn -> out ----
    gemm_fp32<<<dim3(256 / 64, 2048 / 64), 256, 0, stream>>>(hb, W2, g2, 256, 512);
    score_fp32<<<dim3(2048 / 4), 256, 0, stream>>>(g2, a2, sl2, sr2, 256, 256, 1);
    attn_fp32<<<dim3(2048 / 32, 4), 256, 0, stream>>>(g2, sl2, sr2, adj, out, 256, 1, 0, 0);
}